// Round 10
// baseline (1513.671 us; speedup 1.0000x reference)
//
#include <hip/hip_runtime.h>
#include <hip/hip_bf16.h>
#include <math.h>

// Problem constants: T=2048, B=4096, IN_S=1, H=20, OUT_S=1
#define TT 2048
#define BB 4096
#define HH 20

typedef float v2f __attribute__((ext_vector_type(2)));

#define L2E 1.4426950408889634f  // log2(e)

__device__ __forceinline__ float rcp_fast(float x)  { return __builtin_amdgcn_rcpf(x); }
__device__ __forceinline__ float exp2_fast(float x) { return __builtin_amdgcn_exp2f(x); }

__device__ __forceinline__ v2f pk_fma(v2f a, v2f b, v2f c) {
    return __builtin_elementwise_fma(a, b, c);
}
__device__ __forceinline__ v2f exp2v(v2f x) { v2f r; r.x = exp2_fast(x.x); r.y = exp2_fast(x.y); return r; }
__device__ __forceinline__ v2f rcpv(v2f x)  { v2f r; r.x = rcp_fast(x.x);  r.y = rcp_fast(x.y);  return r; }
__device__ __forceinline__ v2f absv(v2f x)  { v2f r; r.x = fabsf(x.x);     r.y = fabsf(x.y);     return r; }
__device__ __forceinline__ v2f csignv(v2f x, v2f s) {
    v2f r; r.x = copysignf(x.x, s.x); r.y = copysignf(x.y, s.y); return r;
}

// R18: TWO independent chain sets (A,B) per wave = 8 batches/wave, software-
// interleaved by the COMPILER inside one instruction stream.
// Why: R17 proved HW wave arbitration cannot overlap two waves' chains
// (stagger = no-op; 2 waves/SIMD cadence ~= serial sum). But the compiler's
// list scheduler CAN overlap two dataflow-independent chains in one basic
// block: B's dot issues inside A's ds_read RT window, A's activation chain
// runs under B's dot issue. Same lanes serve both sets (two register states;
// weights SHARED — same W for every batch; acc-half parking is penalty-free
// per R16). Separate LDS rows (A: 0..79, B: 80..159). All 10 DS reads issued
// up front so lgkmcnt can watermark (A-dot waits at lgkmcnt(5), not 0).
// Cadence model: max(sum-issue ~680cy, C_single ~700cy) per 8 batches vs
// R16's 936cy per 4. 512 blocks = 1 wave/SIMD on half the SIMDs (idle SIMDs
// irrelevant: wall = T x cadence, all blocks concurrent).
// Dead theories: R17 phase-stagger, R16 AGPR-moves, R15 source reorder,
// R13 bpermute, R12 remat.
__global__ __launch_bounds__(64, 1) void lstm_fused_kernel(
    const float* __restrict__ u,      // [T, B, 1]
    const float* __restrict__ W_ih,   // [4H, 1]
    const float* __restrict__ W_hh,   // [4H, H]
    const float* __restrict__ W_out,  // [1, H]
    float* __restrict__ y)            // [T, B, 1]
{
    // A rows: [0..79], B rows: [80..159], scratch for lanes 40..63: [160..207]
    __shared__ __align__(16) float hbuf[224];

    const int lane = threadIdx.x;
    int q = 0, jbase = 0, waA, waB;
    bool is_yA = false, is_yB = false;
    if (lane < 40) {
        q = lane / 10;
        const int p = lane - q * 10;
        jbase = 2 * p;
        waA = q * HH + 2 * p;
        waB = 80 + q * HH + 2 * p;
    } else {
        is_yA = (lane < 44);
        is_yB = (lane >= 44) && (lane < 48);
        waA = 160 + (lane - 40) * 2;  // scratch (written, never read)
        waB = 160 + (lane - 40) * 2;
    }
    // gather-source rows
    const int rbA = is_yA ? (lane - 40) * HH : (lane < 40 ? q * HH : 0);
    const int rbB = 80 + (is_yB ? (lane - 44) * HH : (lane < 40 ? q * HH : 0));

    // h_{-1} = 0 everywhere.
    for (int i = lane; i < 224; i += 64) hbuf[i] = 0.0f;
    asm volatile("" ::: "memory");  // one-time, outside the hot loop

    // ---- Weights (SHARED between sets A and B): rows (g,jbase),(g,jbase+1),
    // k-packed, pre-scaled into exp2 domain: i,f,o * -L2E; g * -2*L2E.
    v2f wgv[4][2][10];
    v2f wihv[4][2];
    const float gsc[4] = {-L2E, -L2E, -2.0f * L2E, -L2E};
    #pragma unroll
    for (int g = 0; g < 4; ++g) {
        #pragma unroll
        for (int r = 0; r < 2; ++r) {
            const int row = g * HH + jbase + r;
            #pragma unroll
            for (int m = 0; m < 10; ++m) {
                wgv[g][r][m].x = gsc[g] * W_hh[row * HH + 2 * m];
                wgv[g][r][m].y = gsc[g] * W_hh[row * HH + 2 * m + 1];
            }
            wihv[g][r].x = gsc[g] * W_ih[row];
            wihv[g][r].y = 0.0f;
        }
    }
    if (lane >= 40) {  // y/idle lanes: gate0/r0 row := W_out (serves A and B)
        #pragma unroll
        for (int m = 0; m < 10; ++m) {
            wgv[0][0][m].x = W_out[2 * m];      // UNSCALED: a[0][0] = dot(W_out, h)
            wgv[0][0][m].y = W_out[2 * m + 1];
        }
        wihv[0][0].x = 0.0f;                    // y has no u-term
    }

    const v2f* hsA = (const v2f*)&hbuf[rbA];   // no restrict: must alias writes
    const v2f* hsB = (const v2f*)&hbuf[rbB];
    v2f* hwA = (v2f*)&hbuf[waA];
    v2f* hwB = (v2f*)&hbuf[waB];

    v2f cvA = {0.0f, 0.0f}, cvB = {0.0f, 0.0f};
    const size_t base = (size_t)blockIdx.x * 8;
    const float* upA = u + base + (lane < 40 ? q : 0);
    const float* upB = u + base + 4 + (lane < 40 ? q : 0);
    float* ypA = y + base + (lane - 40);       // valid on yA lanes
    float* ypB = y + base + 4 + (lane - 44);   // valid on yB lanes

    float u_curA[4], u_curB[4];
    #pragma unroll
    for (int k = 0; k < 4; ++k) { u_curA[k] = upA[(size_t)k * BB]; u_curB[k] = upB[(size_t)k * BB]; }

    const v2f one = {1.0f, 1.0f};
    const v2f n2l2e = {-2.0f * L2E, -2.0f * L2E};

    for (int t4 = 0; t4 < TT; t4 += 4) {
        const int tn = (t4 + 4 < TT) ? (t4 + 4) : t4;
        float u_nxtA[4], u_nxtB[4];
        #pragma unroll
        for (int k = 0; k < 4; ++k) {
            u_nxtA[k] = upA[(size_t)(tn + k) * BB];
            u_nxtB[k] = upB[(size_t)(tn + k) * BB];
        }

        float y4A[4], y4B[4];  // y lanes: y_{t-1} (gather sees h one step back)

        #pragma unroll
        for (int tt = 0; tt < 4; ++tt) {
            // ---- issue ALL 10 ds_read_b128 up front (A then B) so the
            // compiler can watermark lgkmcnt (A-dot at lgkmcnt(5)) ----
            v2f h2A[10], h2B[10];
            #pragma unroll
            for (int m = 0; m < 10; ++m) h2A[m] = hsA[m];
            #pragma unroll
            for (int m = 0; m < 10; ++m) h2B[m] = hsB[m];

            const float uvA = u_curA[tt];
            const float uvB = u_curB[tt];
            const v2f uv2A = {uvA, uvA};
            const v2f uv2B = {uvB, uvB};
            v2f aA[4][2], aB[4][2];
            #pragma unroll
            for (int g = 0; g < 4; ++g) {
                #pragma unroll
                for (int r = 0; r < 2; ++r) {
                    aA[g][r] = wihv[g][r] * uv2A;
                    aB[g][r] = wihv[g][r] * uv2B;
                }
            }

            // ---- dot A (80 pk_fma) ----
            #pragma unroll
            for (int m = 0; m < 10; ++m) {
                const v2f hp = h2A[m];
                aA[2][0] = pk_fma(wgv[2][0][m], hp, aA[2][0]);
                aA[2][1] = pk_fma(wgv[2][1][m], hp, aA[2][1]);
                aA[1][0] = pk_fma(wgv[1][0][m], hp, aA[1][0]);
                aA[1][1] = pk_fma(wgv[1][1][m], hp, aA[1][1]);
                aA[0][0] = pk_fma(wgv[0][0][m], hp, aA[0][0]);
                aA[0][1] = pk_fma(wgv[0][1][m], hp, aA[0][1]);
                aA[3][0] = pk_fma(wgv[3][0][m], hp, aA[3][0]);
                aA[3][1] = pk_fma(wgv[3][1][m], hp, aA[3][1]);
            }
            // ---- dot B (80 pk_fma) — independent of everything in A ----
            #pragma unroll
            for (int m = 0; m < 10; ++m) {
                const v2f hp = h2B[m];
                aB[2][0] = pk_fma(wgv[2][0][m], hp, aB[2][0]);
                aB[2][1] = pk_fma(wgv[2][1][m], hp, aB[2][1]);
                aB[1][0] = pk_fma(wgv[1][0][m], hp, aB[1][0]);
                aB[1][1] = pk_fma(wgv[1][1][m], hp, aB[1][1]);
                aB[0][0] = pk_fma(wgv[0][0][m], hp, aB[0][0]);
                aB[0][1] = pk_fma(wgv[0][1][m], hp, aB[0][1]);
                aB[3][0] = pk_fma(wgv[3][0][m], hp, aB[3][0]);
                aB[3][1] = pk_fma(wgv[3][1][m], hp, aB[3][1]);
            }

            // ---- activations A ----
            {
                v2f gi, gf, gg, go;
                gi.x = aA[0][0].x + aA[0][0].y;  gi.y = aA[0][1].x + aA[0][1].y;
                gf.x = aA[1][0].x + aA[1][0].y;  gf.y = aA[1][1].x + aA[1][1].y;
                gg.x = aA[2][0].x + aA[2][0].y;  gg.y = aA[2][1].x + aA[2][1].y;
                go.x = aA[3][0].x + aA[3][0].y;  go.y = aA[3][1].x + aA[3][1].y;
                y4A[tt] = gi.x;

                const v2f eg = exp2v(gg);
                const v2f ef = exp2v(gf);
                const v2f ei = exp2v(gi);
                const v2f eo = exp2v(go);
                const v2f pg = one + eg, pf = one + ef, pi2 = one + ei, po = one + eo;
                const v2f mg = one - eg;

                const v2f m1  = pg * pi2;
                const v2f num = pk_fma(cvA, m1, mg * pf);
                const v2f rv  = rcpv(pf * m1);
                cvA = num * rv;
                const v2f kn  = absv(num) * n2l2e;
                const v2f ec  = exp2v(kn * rv);
                const v2f pc  = one + ec;
                const v2f mcs = csignv(one - ec, num);
                const v2f hv  = mcs * rcpv(po * pc);
                *hwA = hv;
            }
            // ---- activations B ----
            {
                v2f gi, gf, gg, go;
                gi.x = aB[0][0].x + aB[0][0].y;  gi.y = aB[0][1].x + aB[0][1].y;
                gf.x = aB[1][0].x + aB[1][0].y;  gf.y = aB[1][1].x + aB[1][1].y;
                gg.x = aB[2][0].x + aB[2][0].y;  gg.y = aB[2][1].x + aB[2][1].y;
                go.x = aB[3][0].x + aB[3][0].y;  go.y = aB[3][1].x + aB[3][1].y;
                y4B[tt] = gi.x;

                const v2f eg = exp2v(gg);
                const v2f ef = exp2v(gf);
                const v2f ei = exp2v(gi);
                const v2f eo = exp2v(go);
                const v2f pg = one + eg, pf = one + ef, pi2 = one + ei, po = one + eo;
                const v2f mg = one - eg;

                const v2f m1  = pg * pi2;
                const v2f num = pk_fma(cvB, m1, mg * pf);
                const v2f rv  = rcpv(pf * m1);
                cvB = num * rv;
                const v2f kn  = absv(num) * n2l2e;
                const v2f ec  = exp2v(kn * rv);
                const v2f pc  = one + ec;
                const v2f mcs = csignv(one - ec, num);
                const v2f hv  = mcs * rcpv(po * pc);
                *hwB = hv;
            }
        }

        if (is_yA) {
            #pragma unroll
            for (int k = 0; k < 4; ++k) {
                const int idx = t4 - 1 + k;
                if (idx >= 0) ypA[(size_t)idx * BB] = y4A[k];
            }
        }
        if (is_yB) {
            #pragma unroll
            for (int k = 0; k < 4; ++k) {
                const int idx = t4 - 1 + k;
                if (idx >= 0) ypB[(size_t)idx * BB] = y4B[k];
            }
        }

        #pragma unroll
        for (int k = 0; k < 4; ++k) { u_curA[k] = u_nxtA[k]; u_curB[k] = u_nxtB[k]; }
    }

    // Epilogue: y_{T-1} from the final h (both sets).
    {
        v2f ayA = {0.0f, 0.0f}, ayB = {0.0f, 0.0f};
        #pragma unroll
        for (int m = 0; m < 10; ++m) {
            ayA = pk_fma(wgv[0][0][m], hsA[m], ayA);
            ayB = pk_fma(wgv[0][0][m], hsB[m], ayB);
        }
        if (is_yA) ypA[(size_t)(TT - 1) * BB] = ayA.x + ayA.y;
        if (is_yB) ypB[(size_t)(TT - 1) * BB] = ayB.x + ayB.y;
    }
}

extern "C" void kernel_launch(void* const* d_in, const int* in_sizes, int n_in,
                              void* d_out, int out_size, void* d_ws, size_t ws_size,
                              hipStream_t stream) {
    const float* u     = (const float*)d_in[0];   // [2048, 4096, 1]
    const float* W_ih  = (const float*)d_in[1];   // [80, 1]
    const float* W_hh  = (const float*)d_in[2];   // [80, 20]
    const float* W_out = (const float*)d_in[3];   // [1, 20]
    float* y = (float*)d_out;                      // [2048, 4096, 1]

    const int blocks = BB / 8;  // 8 batches (2 chain sets) per single-wave block
    lstm_fused_kernel<<<dim3(blocks), dim3(64), 0, stream>>>(u, W_ih, W_hh, W_out, y);
}

// Round 11
// 729.873 us; speedup vs baseline: 2.0739x; 2.0739x over previous
//
#include <hip/hip_runtime.h>
#include <hip/hip_bf16.h>
#include <math.h>

// Problem constants: T=2048, B=4096, IN_S=1, H=20, OUT_S=1
#define TT 2048
#define BB 4096
#define HH 20

typedef float v2f __attribute__((ext_vector_type(2)));

#define L2E 1.4426950408889634f  // log2(e)

__device__ __forceinline__ float rcp_fast(float x)  { return __builtin_amdgcn_rcpf(x); }
__device__ __forceinline__ float exp2_fast(float x) { return __builtin_amdgcn_exp2f(x); }

__device__ __forceinline__ v2f pk_fma(v2f a, v2f b, v2f c) {
    return __builtin_elementwise_fma(a, b, c);
}
__device__ __forceinline__ v2f exp2v(v2f x) { v2f r; r.x = exp2_fast(x.x); r.y = exp2_fast(x.y); return r; }
__device__ __forceinline__ v2f rcpv(v2f x)  { v2f r; r.x = rcp_fast(x.x);  r.y = rcp_fast(x.y);  return r; }
__device__ __forceinline__ v2f absv(v2f x)  { v2f r; r.x = fabsf(x.x);     r.y = fabsf(x.y);     return r; }
__device__ __forceinline__ v2f csignv(v2f x, v2f s) {
    v2f r; r.x = copysignf(x.x, s.x); r.y = copysignf(x.y, s.y); return r;
}

// R19: restore the best structure (R16: 4 batches/wave, 2 units/lane,
// 1 wave/SIMD, 742us) + final trim: two-phase 16-step unroll eliminates the
// u_cur<-u_nxt register copies (phase A consumes uA while prefetching uB,
// phase B consumes uB while prefetching uA). No other change.
// SESSION MODEL (R18-confirmed): per-SIMD throughput is ~940cy per 4
// batch-steps REGARDLESS of organization (2b x 2w = 967, 4b x 1w = 937,
// 8b x 1w = 1848/2 = 924). C scales linearly with per-wave inst count
// (~4.5cy effective/inst); the compiler produces ZERO overlap between
// independent chains in one stream (R18), HW produces ~none across waves
// (R10/R17). Per-step stream ~140 insts is near-irreducible (80 pk_fma =
// the 160 MACs; 14 trans minimal; merged-denominator algebra already
// 2 rcp/unit). Dead levers: bpermute gather (R13), source reorder (R15),
// reg pins (R12/R16), phase stagger (R17), dual-chain interleave (R18).
__global__ __launch_bounds__(64, 1) void lstm_fused_kernel(
    const float* __restrict__ u,      // [T, B, 1]
    const float* __restrict__ W_ih,   // [4H, 1]
    const float* __restrict__ W_hh,   // [4H, H]
    const float* __restrict__ W_out,  // [1, H]
    float* __restrict__ y)            // [T, B, 1]
{
    // hbuf[0..79]  = h for 4 batches x 20 units
    // hbuf[80..127] = scratch for y/idle lane writes (keeps the stream uniform)
    __shared__ __align__(16) float hbuf[128];

    const int lane = threadIdx.x;
    int q, wa, jbase;
    bool is_y = false;
    if (lane < 40) {
        q = lane / 10;
        const int p = lane - q * 10;
        wa = q * HH + 2 * p;          // write offset (floats), 8B-aligned
        jbase = 2 * p;
    } else {
        is_y = (lane < 44);
        q = is_y ? (lane - 40) : 0;   // y-lane reads its batch's h
        wa = 4 * HH + (lane - 40) * 2; // scratch area
        jbase = 0;
    }

    // h_{-1} = 0 everywhere.
    for (int i = lane; i < 128; i += 64) hbuf[i] = 0.0f;
    asm volatile("" ::: "memory");  // one-time, outside the hot loop

    // ---- Weights: per lane, rows (g, jbase) and (g, jbase+1), k-packed.
    // Pre-scaled into exp2 domain: i,f,o rows * -log2(e); g row * -2*log2(e).
    v2f wgv[4][2][10];
    v2f wihv[4][2];
    const float gsc[4] = {-L2E, -L2E, -2.0f * L2E, -L2E};
    #pragma unroll
    for (int g = 0; g < 4; ++g) {
        #pragma unroll
        for (int r = 0; r < 2; ++r) {
            const int row = g * HH + jbase + r;
            #pragma unroll
            for (int m = 0; m < 10; ++m) {
                wgv[g][r][m].x = gsc[g] * W_hh[row * HH + 2 * m];
                wgv[g][r][m].y = gsc[g] * W_hh[row * HH + 2 * m + 1];
            }
            wihv[g][r].x = gsc[g] * W_ih[row];
            wihv[g][r].y = 0.0f;
        }
    }
    if (lane >= 40) {  // y/idle lanes: gate0/r0 row := W_out
        #pragma unroll
        for (int m = 0; m < 10; ++m) {
            wgv[0][0][m].x = W_out[2 * m];      // UNSCALED: a[0][0] = dot(W_out, h)
            wgv[0][0][m].y = W_out[2 * m + 1];
        }
        wihv[0][0].x = 0.0f;                    // y has no u-term
    }

    const v2f* hs = (const v2f*)&hbuf[q * HH];  // 16B-aligned (q*80 bytes)
    v2f* hw = (v2f*)&hbuf[wa];                  // no restrict: must alias hs

    v2f cv = {0.0f, 0.0f};
    const float* __restrict__ up = u + (size_t)blockIdx.x * 4 + q;
    float* yp = y + (size_t)blockIdx.x * 4 + (lane - 40);  // valid on y-lanes

    const v2f one = {1.0f, 1.0f};
    const v2f n2l2e = {-2.0f * L2E, -2.0f * L2E};

    // one full LSTM step; returns the gate-0 hadd (on y-lanes: y_{t-1})
    auto step = [&](float uv) -> float {
        // ---- gather own batch's h_{t-1}: 5 x ds_read_b128 ----
        v2f h2[10];
        #pragma unroll
        for (int m = 0; m < 10; ++m) h2[m] = hs[m];

        const v2f uv2 = {uv, uv};
        v2f a[4][2];
        #pragma unroll
        for (int g = 0; g < 4; ++g) {
            #pragma unroll
            for (int r = 0; r < 2; ++r) a[g][r] = wihv[g][r] * uv2;
        }

        // 80 v_pk_fma_f32; 8 accumulators round-robin -> 16cy dep spacing.
        #pragma unroll
        for (int m = 0; m < 10; ++m) {
            const v2f hp = h2[m];
            a[2][0] = pk_fma(wgv[2][0][m], hp, a[2][0]);
            a[2][1] = pk_fma(wgv[2][1][m], hp, a[2][1]);
            a[1][0] = pk_fma(wgv[1][0][m], hp, a[1][0]);
            a[1][1] = pk_fma(wgv[1][1][m], hp, a[1][1]);
            a[0][0] = pk_fma(wgv[0][0][m], hp, a[0][0]);
            a[0][1] = pk_fma(wgv[0][1][m], hp, a[0][1]);
            a[3][0] = pk_fma(wgv[3][0][m], hp, a[3][0]);
            a[3][1] = pk_fma(wgv[3][1][m], hp, a[3][1]);
        }
        // preacts packed (j0, j1) per gate
        v2f gi, gf, gg, go;
        gi.x = a[0][0].x + a[0][0].y;  gi.y = a[0][1].x + a[0][1].y;
        gf.x = a[1][0].x + a[1][0].y;  gf.y = a[1][1].x + a[1][1].y;
        gg.x = a[2][0].x + a[2][0].y;  gg.y = a[2][1].x + a[2][1].y;
        go.x = a[3][0].x + a[3][0].y;  go.y = a[3][1].x + a[3][1].y;

        // ---- activations, v2f (two independent j-chains interleave):
        // 10 exp2 + 4 rcp per lane, merged denominators (R9/R10 algebra).
        const v2f eg = exp2v(gg);   // e^{-2 x_g}
        const v2f ef = exp2v(gf);   // e^{-x_f}
        const v2f ei = exp2v(gi);   // e^{-x_i}
        const v2f eo = exp2v(go);   // e^{-x_o}
        const v2f pg = one + eg, pf = one + ef, pi2 = one + ei, po = one + eo;
        const v2f mg = one - eg;    // tanh(x_g) sign falls out naturally

        const v2f m1  = pg * pi2;
        const v2f num = pk_fma(cv, m1, mg * pf);
        const v2f rv  = rcpv(pf * m1);
        cv = num * rv;                                // next step only
        const v2f kn  = absv(num) * n2l2e;            // overlaps the rcp
        const v2f ec  = exp2v(kn * rv);               // e^{-2|c|} <= 1
        const v2f pc  = one + ec;
        const v2f mcs = csignv(one - ec, num);        // sign(c)==sign(num)
        const v2f hv  = mcs * rcpv(po * pc);

        // ---- publish h_t: one ds_write_b64 (compiler orders vs gather) ----
        *hw = hv;
        return gi.x;
    };

    float uA[8], uB[8];
    #pragma unroll
    for (int k = 0; k < 8; ++k) uA[k] = up[(size_t)k * BB];

    for (int t16 = 0; t16 < TT; t16 += 16) {
        // ---- pins: weights live in arch VGPRs across the hot loop (R16) ----
        #pragma unroll
        for (int g = 0; g < 4; ++g) {
            #pragma unroll
            for (int r = 0; r < 2; ++r) {
                #pragma unroll
                for (int m = 0; m < 10; ++m)
                    asm volatile("" : "+v"(wgv[g][r][m].x), "+v"(wgv[g][r][m].y));
                asm volatile("" : "+v"(wihv[g][r].x));
            }
        }

        float yA[8], yB[8];

        // ---- phase A: consume uA (steps t16..t16+7), prefetch uB ----
        #pragma unroll
        for (int k = 0; k < 8; ++k) uB[k] = up[(size_t)(t16 + 8 + k) * BB];
        #pragma unroll
        for (int k = 0; k < 8; ++k) yA[k] = step(uA[k]);
        if (is_y) {
            #pragma unroll
            for (int k = 0; k < 8; ++k) {
                const int idx = t16 - 1 + k;
                if (idx >= 0) yp[(size_t)idx * BB] = yA[k];
            }
        }

        // ---- phase B: consume uB (steps t16+8..t16+15), prefetch next uA ----
        {
            const int tn = (t16 + 16 < TT) ? (t16 + 16) : t16;
            #pragma unroll
            for (int k = 0; k < 8; ++k) uA[k] = up[(size_t)(tn + k) * BB];
        }
        #pragma unroll
        for (int k = 0; k < 8; ++k) yB[k] = step(uB[k]);
        if (is_y) {
            #pragma unroll
            for (int k = 0; k < 8; ++k) {
                yp[(size_t)(t16 + 7 + k) * BB] = yB[k];  // idx >= 7 always
            }
        }
    }

    // Epilogue: y_{T-1} from the final h (y-lanes only).
    {
        v2f ay = {0.0f, 0.0f};
        #pragma unroll
        for (int m = 0; m < 10; ++m) ay = pk_fma(wgv[0][0][m], hs[m], ay);
        if (is_y) yp[(size_t)(TT - 1) * BB] = ay.x + ay.y;
    }
}

extern "C" void kernel_launch(void* const* d_in, const int* in_sizes, int n_in,
                              void* d_out, int out_size, void* d_ws, size_t ws_size,
                              hipStream_t stream) {
    const float* u     = (const float*)d_in[0];   // [2048, 4096, 1]
    const float* W_ih  = (const float*)d_in[1];   // [80, 1]
    const float* W_hh  = (const float*)d_in[2];   // [80, 20]
    const float* W_out = (const float*)d_in[3];   // [1, 20]
    float* y = (float*)d_out;                      // [2048, 4096, 1]

    const int blocks = BB / 4;  // 4 batches per single-wave block -> 1024 = 1 wave/SIMD
    lstm_fused_kernel<<<dim3(blocks), dim3(64), 0, stream>>>(u, W_ih, W_hh, W_out, y);
}